// Round 19
// baseline (42.631 us; speedup 1.0000x reference)
//
#include <hip/hip_runtime.h>

// GraphPooling: out[v] = mean over in-neighbors of h[src], else h[v] if deg==0.
// 65536 nodes x 64 f32 features, E = 1,048,576 edges.
//
// TWO dispatches, zero global atomics, zero memsets:
//   k_build  : R17/R18 sort (int4 edge reads + LDS dst staging, d&127 payload)
//              with offs written TRANSPOSED [bucket][pblock] (R19 isolated
//              test -- R9 bundled it with a bad gather layout; never isolated).
//   k_gather : R18 verbatim except offs reads are now two contiguous 512 B
//              rows per block (8 lines vs 256): 512 blocks x 1024 thr, bucket
//              QUAD (128 nodes), XCD-swizzled, 128-bin LDS sort, node-pair
//              gather core.
// Lessons: no coop grid.sync (R14), no LDS float atomics (R5), wave-uniform
// shfl (R3), 16-lane/edge core (R9/R12/R15), XCD swizzle (R13), quad (R18).

#define NBUCK 2048     // 32 nodes per bucket (build side)
#define NPBLK 256      // partition blocks; epb = E/NPBLK = 4096 (fits u16)
#define NPT   8        // NBUCK / 256 buckets owned per thread in build scan
#define GBLK  512      // gather blocks (bucket quads)
#define QUADCAP 4096   // cap for a bucket-quad (mean 2048, sigma ~45)
#define EPBMAX 4096    // LDS dst staging capacity (ints)

template <bool BF16>
__global__ __launch_bounds__(256) void k_build(
        const float* __restrict__ h,
        const int* __restrict__ src,
        const int* __restrict__ dst,
        unsigned int* __restrict__ pairs,      // [NPBLK * epb]
        unsigned short* __restrict__ offs,     // [NBUCK+1][NPBLK] TRANSPOSED
        uint4* __restrict__ hbf,               // bf16 table (8 f32 -> 1 uint4)
        int E, int epb, int n8) {
    int t = threadIdx.x;
    int bid = blockIdx.x;

    if (bid >= NPBLK) {
        // ---- cvt part: f32 -> packed bf16 (RNE) ----
        if (!BF16) return;
        int i = (bid - NPBLK) * 256 + t;
        if (i >= n8) return;
        const float4* h4 = (const float4*)h;
        float4 a = h4[2 * i], bq = h4[2 * i + 1];
        auto pk = [](float lo, float hi) {
            unsigned int ul = __float_as_uint(lo), uh = __float_as_uint(hi);
            unsigned int rl = (ul + 0x7FFFu + ((ul >> 16) & 1u)) >> 16;
            unsigned int rh = (uh + 0x7FFFu + ((uh >> 16) & 1u)) & 0xFFFF0000u;
            return rl | rh;
        };
        hbf[i] = make_uint4(pk(a.x, a.y), pk(a.z, a.w), pk(bq.x, bq.y), pk(bq.z, bq.w));
        return;
    }

    // ---- partition part: local counting sort of this block's edge slice ----
    __shared__ unsigned int hist[NBUCK];    // reused as absolute cursors
    __shared__ uint4 dstbuf4[EPBMAX / 4];   // staged dst values (16 KB)
    __shared__ unsigned int wpart[4];
    for (int i = t; i < NBUCK; i += 256) hist[i] = 0u;
    __syncthreads();

    int base = bid * epb;
    int cnt = E - base; if (cnt > epb) cnt = epb; if (cnt < 0) cnt = 0;
    int nv = cnt >> 2;                      // int4 groups (epb % 4 == 0)

    // Hist pass: int4 reads (4 edges/iter), stage dst in LDS.
    const int4* d4 = (const int4*)(dst + base);
    for (int i = t; i < nv; i += 256) {
        int4 d = d4[i];
        dstbuf4[i] = make_uint4((unsigned)d.x, (unsigned)d.y,
                                (unsigned)d.z, (unsigned)d.w);
        atomicAdd(&hist[((unsigned)d.x) >> 5], 1u);
        atomicAdd(&hist[((unsigned)d.y) >> 5], 1u);
        atomicAdd(&hist[((unsigned)d.z) >> 5], 1u);
        atomicAdd(&hist[((unsigned)d.w) >> 5], 1u);
    }
    for (int i = nv * 4 + t; i < cnt; i += 256)          // tail (rare)
        atomicAdd(&hist[((unsigned)dst[base + i]) >> 5], 1u);
    __syncthreads();

    // Block-exclusive scan over 2048 bins; thread t owns bins t*8..t*8+7.
    unsigned int loc[NPT], lsum = 0u;
    #pragma unroll
    for (int i = 0; i < NPT; ++i) { loc[i] = hist[t * NPT + i]; lsum += loc[i]; }
    int lane = t & 63, wid = t >> 6;
    unsigned int x = lsum;
    #pragma unroll
    for (int off = 1; off < 64; off <<= 1) {
        unsigned int y = __shfl_up(x, off);
        if (lane >= off) x += y;
    }
    if (lane == 63) wpart[wid] = x;
    __syncthreads();
    if (wid == 0) {                        // full-wave scan of 4 partials
        unsigned int w = (lane < 4) ? wpart[lane] : 0u;
        #pragma unroll
        for (int off = 1; off < 4; off <<= 1) {
            unsigned int y = __shfl_up(w, off);
            if (lane >= off) w += y;
        }
        if (lane < 4) wpart[lane] = w;
    }
    __syncthreads();
    unsigned int run = (wid ? wpart[wid - 1] : 0u) + x - lsum;

    // Transposed offs writes: offs[bucket * NPBLK + bid].
    #pragma unroll
    for (int i = 0; i < NPT; ++i) {
        offs[(size_t)(t * NPT + i) * NPBLK + bid] = (unsigned short)run;
        hist[t * NPT + i] = (unsigned)base + run;      // absolute cursor
        run += loc[i];
    }
    if (t == 255) offs[(size_t)NBUCK * NPBLK + bid] = (unsigned short)cnt;
    __syncthreads();

    // Scatter pass: int4 src reads, dst from LDS; payload packs d&127
    // (node within BUCKET QUAD). Writes confined to [base, base+cnt).
    const int4* s4 = (const int4*)(src + base);
    for (int i = t; i < nv; i += 256) {
        int4 s = s4[i];
        uint4 d = dstbuf4[i];
        unsigned int p0 = atomicAdd(&hist[d.x >> 5], 1u);
        pairs[p0] = (unsigned)s.x | ((d.x & 127u) << 16);
        unsigned int p1 = atomicAdd(&hist[d.y >> 5], 1u);
        pairs[p1] = (unsigned)s.y | ((d.y & 127u) << 16);
        unsigned int p2 = atomicAdd(&hist[d.z >> 5], 1u);
        pairs[p2] = (unsigned)s.z | ((d.z & 127u) << 16);
        unsigned int p3 = atomicAdd(&hist[d.w >> 5], 1u);
        pairs[p3] = (unsigned)s.w | ((d.w & 127u) << 16);
    }
    for (int i = nv * 4 + t; i < cnt; i += 256) {        // tail (rare)
        unsigned int d = (unsigned)dst[base + i];
        unsigned int s = (unsigned)src[base + i];
        unsigned int pos = atomicAdd(&hist[d >> 5], 1u);
        pairs[pos] = s | ((d & 127u) << 16);
    }
}

// One block (16 waves, 1024 thr) per bucket QUAD (128 nodes).
template <bool BF16>
__global__ __launch_bounds__(1024) void k_gather(
        const float* __restrict__ h,          // f32 original (deg==0 fallback)
        const uint2* __restrict__ hbf,        // bf16 table, 16 uint2/node
        const unsigned int* __restrict__ pairs,
        const unsigned short* __restrict__ offs,   // [NBUCK+1][NPBLK]
        float* __restrict__ out, int epb) {
    __shared__ unsigned int pairbuf[QUADCAP];        // 16 KB
    __shared__ unsigned short ssrc[QUADCAP];         // 8 KB
    __shared__ unsigned int hist[128], offl[128], cur[128];
    __shared__ unsigned int wpart[16];
    int t = threadIdx.x;
    // XCD-aware swizzle over 512 bucket-quads (bijective: 512 % 8 == 0).
    int B = blockIdx.x;
    int g = (B & 7) * (GBLK / 8) + (B >> 3);
    int b4 = 4 * g;                        // first bucket of the quad
    if (t < 128) hist[t] = 0u;

    // Phase A: 4 threads per pblock; transposed offs -> two contiguous rows.
    int p = t >> 2, q = t & 3;             // p in 0..255
    unsigned int s0 = offs[(size_t)b4 * NPBLK + p];
    unsigned int s4v = offs[(size_t)(b4 + 4) * NPBLK + p];
    unsigned int runlen = s4v - s0;
    unsigned int contrib = (q == 0) ? runlen : 0u;

    // Block scan (16 waves) of contributions -> placement.
    int lane = t & 63, wid = t >> 6;
    unsigned int x = contrib;
    #pragma unroll
    for (int off = 1; off < 64; off <<= 1) {
        unsigned int y = __shfl_up(x, off);
        if (lane >= off) x += y;
    }
    if (lane == 63) wpart[wid] = x;
    __syncthreads();                       // also covers hist zero
    if (wid == 0) {                        // full-wave scan of 16 partials
        unsigned int w = (lane < 16) ? wpart[lane] : 0u;
        #pragma unroll
        for (int off = 1; off < 16; off <<= 1) {
            unsigned int y = __shfl_up(w, off);
            if (lane >= off) w += y;
        }
        if (lane < 16) wpart[lane] = w;
    }
    __syncthreads();
    unsigned int e = (wid ? wpart[wid - 1] : 0u) + x - contrib;  // excl prefix
    unsigned int mypos = e - (q ? runlen : 0u);    // pblock p's placement
    unsigned int cnt = min(wpart[15], (unsigned)QUADCAP);
    if (mypos >= cnt) runlen = 0u;
    else if (mypos + runlen > cnt) runlen = cnt - mypos;

    // Interleaved copy: thread q of the 4 handles k = q, q+4, ...
    for (unsigned int k = (unsigned)q; k < runlen; k += 4u) {
        unsigned int pr = pairs[(size_t)p * epb + s0 + k];
        pairbuf[mypos + k] = pr;
        atomicAdd(&hist[pr >> 16], 1u);
    }
    __syncthreads();

    // Exclusive scan of 128 node counts on wave 0 (2 bins per lane).
    if (t < 64) {
        unsigned int v0 = hist[2 * t], v1 = hist[2 * t + 1];
        unsigned int v = v0 + v1;
        unsigned int xx = v;
        #pragma unroll
        for (int off = 1; off < 64; off <<= 1) {
            unsigned int y = __shfl_up(xx, off);
            if (t >= off) xx += y;
        }
        unsigned int excl = xx - v;
        offl[2 * t] = excl;          cur[2 * t] = excl;
        offl[2 * t + 1] = excl + v0; cur[2 * t + 1] = excl + v0;
    }
    __syncthreads();

    // LDS scatter into per-node sorted order (u16 src payload).
    for (unsigned int i = t; i < cnt; i += 1024u) {
        unsigned int pr = pairbuf[i];
        unsigned int pos = atomicAdd(&cur[pr >> 16], 1u);
        ssrc[pos] = (unsigned short)(pr & 0xFFFFu);
    }
    __syncthreads();

    // Gather: wave w (0..15) handles nodes w*8 .. w*8+7, processed as 4 pairs.
    int w = t >> 6;
    int egrp = lane >> 4, fq = lane & 15;
    const float4* h4 = (const float4*)h;
    float4* out4 = (float4*)out;

    for (int np = 0; np < 4; ++np) {
        int na = w * 8 + np * 2;
        int nb = na + 1;
        unsigned int sa = offl[na], da = hist[na];
        unsigned int sb = offl[nb], db = hist[nb];
        float4 accA = make_float4(0.f, 0.f, 0.f, 0.f);
        float4 accB = make_float4(0.f, 0.f, 0.f, 0.f);
        unsigned int dmax = max(da, db);
        for (unsigned int base = 0; base < dmax; base += 64u) {
            int ca = (int)min(64u, (da > base) ? (da - base) : 0u);  // uniform
            int cb = (int)min(64u, (db > base) ? (db - base) : 0u);  // uniform
            int ia = (lane < ca) ? (int)ssrc[sa + base + lane] : 0;
            int ib = (lane < cb) ? (int)ssrc[sb + base + lane] : 0;
            int cm = (ca > cb) ? ca : cb;
            int nit = (cm + 3) >> 2;                     // wave-uniform
            for (int it = 0; it < nit; ++it) {
                int j = it * 4 + egrp;
                int sA = __shfl(ia, (j < ca) ? j : 0);   // all lanes active
                int sB = __shfl(ib, (j < cb) ? j : 0);
                if (BF16) {
                    uint2 mA = hbf[(size_t)sA * 16 + fq];
                    uint2 mB = hbf[(size_t)sB * 16 + fq];
                    if (j < ca) {
                        accA.x += __uint_as_float(mA.x << 16);
                        accA.y += __uint_as_float(mA.x & 0xFFFF0000u);
                        accA.z += __uint_as_float(mA.y << 16);
                        accA.w += __uint_as_float(mA.y & 0xFFFF0000u);
                    }
                    if (j < cb) {
                        accB.x += __uint_as_float(mB.x << 16);
                        accB.y += __uint_as_float(mB.x & 0xFFFF0000u);
                        accB.z += __uint_as_float(mB.y << 16);
                        accB.w += __uint_as_float(mB.y & 0xFFFF0000u);
                    }
                } else {
                    float4 mA = h4[(size_t)sA * 16 + fq];
                    float4 mB = h4[(size_t)sB * 16 + fq];
                    if (j < ca) {
                        accA.x += mA.x; accA.y += mA.y; accA.z += mA.z; accA.w += mA.w;
                    }
                    if (j < cb) {
                        accB.x += mB.x; accB.y += mB.y; accB.z += mB.z; accB.w += mB.w;
                    }
                }
            }
        }
        // Butterfly-reduce both acc chains (xor 16, 32); sum lands in ALL lanes.
        #pragma unroll
        for (int k = 16; k <= 32; k <<= 1) {
            accA.x += __shfl_xor(accA.x, k);
            accA.y += __shfl_xor(accA.y, k);
            accA.z += __shfl_xor(accA.z, k);
            accA.w += __shfl_xor(accA.w, k);
            accB.x += __shfl_xor(accB.x, k);
            accB.y += __shfl_xor(accB.y, k);
            accB.z += __shfl_xor(accB.z, k);
            accB.w += __shfl_xor(accB.w, k);
        }
        // Lanes 0-15 store node A, lanes 16-31 store node B.
        if (lane < 32) {
            int n = (lane < 16) ? na : nb;
            unsigned int dg = (lane < 16) ? da : db;
            float4 acc = (lane < 16) ? accA : accB;
            size_t oi = ((size_t)g * 128 + n) * 16 + fq;
            float4 r;
            if (dg > 0u) {
                float inv = 1.0f / (float)dg;
                r = make_float4(acc.x * inv, acc.y * inv, acc.z * inv, acc.w * inv);
            } else {
                r = h4[oi];               // exact f32 copy
            }
            out4[oi] = r;
        }
    }
}

extern "C" void kernel_launch(void* const* d_in, const int* in_sizes, int n_in,
                              void* d_out, int out_size, void* d_ws, size_t ws_size,
                              hipStream_t stream) {
    const float* h = (const float*)d_in[0];
    const int* src = (const int*)d_in[1];
    const int* dst = (const int*)d_in[2];
    float* out = (float*)d_out;
    int E = in_sizes[1];
    int nodes = out_size / 64;        // 65536

    int epb = ((E + NPBLK - 1) / NPBLK + 255) & ~255;   // 4096 for E=1M

    // ws layout: pairs 4MB | offs 1.05MB | hbf 8MB
    unsigned int* pairs  = (unsigned int*)d_ws;
    unsigned short* offs = (unsigned short*)(pairs + (size_t)NPBLK * epb);
    size_t offs_elems = (size_t)(NBUCK + 1) * NPBLK;
    size_t offs_bytes = (offs_elems * 2 + 15) & ~(size_t)15;
    uint4* hbf = (uint4*)((char*)offs + offs_bytes);

    size_t need_base = (size_t)NPBLK * epb * 4 + offs_bytes;
    size_t need_bf   = need_base + (size_t)nodes * 64 * 2;
    bool use_bf = (ws_size >= need_bf);

    int n8 = nodes * 64 / 8;                      // uint4 outputs for cvt
    int cvtblocks = (n8 + 255) / 256;

    if (use_bf) {
        k_build<true><<<NPBLK + cvtblocks, 256, 0, stream>>>(
            h, src, dst, pairs, offs, hbf, E, epb, n8);
        k_gather<true><<<GBLK, 1024, 0, stream>>>(
            h, (const uint2*)hbf, pairs, offs, out, epb);
    } else {
        k_build<false><<<NPBLK, 256, 0, stream>>>(
            h, src, dst, pairs, offs, hbf, E, epb, n8);
        k_gather<false><<<GBLK, 1024, 0, stream>>>(
            h, (const uint2*)hbf, pairs, offs, out, epb);
    }
}

// Round 20
// 40.003 us; speedup vs baseline: 1.0657x; 1.0657x over previous
//
#include <hip/hip_runtime.h>

// GraphPooling: out[v] = mean over in-neighbors of h[src], else h[v] if deg==0.
// 65536 nodes x 64 f32 features, E = 1,048,576 edges.
//
// R18 configuration (best measured: 40.0 us), restored after R19's isolated
// offs-transpose test regressed (42.6 -- scattered build writes cost more
// than the L2-resident gather reads saved; R12 theory now MEASURED).
//
// TWO dispatches, zero global atomics, zero memsets:
//   k_build  : blocks [0,256): partition-local counting sort, int4 edge reads
//              + LDS dst staging, payload packs d&127 (node within bucket
//              QUAD); offs [pblock][bucket]. blocks [256,...): f32->bf16 (RNE).
//   k_gather : 512 blocks x 1024 thr; block g owns bucket quad {4g..4g+3} =
//              128 nodes (XCD-swizzled). Phase A: 4 threads per pblock read
//              the combined 4-bucket run (contiguous in pairs), interleaved
//              copy. 128-bin LDS sort; phase C = node-pair gather core,
//              16 waves x 8 nodes.
// Occupancy: 1024 thr x 2 blk/CU = 2048 thr/CU (max); LDS 26.2 KB/blk.
// Closed hypotheses: coop grid.sync (R14: 299us), LDS float atomics (R5:
// 359us), 8-lane/edge layout (R9), NPBLK=128 (R10), inner unroll (R12),
// direct-LDS ssrc (R15), offs transpose (R19). Landed: bf16 table (R6),
// XCD swizzle (R13), bucket-pair (R16), quad+int4 build (R17/R18).

#define NBUCK 2048     // 32 nodes per bucket (build side)
#define NPBLK 256      // partition blocks; epb = E/NPBLK = 4096 (fits u16)
#define NPT   8        // NBUCK / 256 buckets owned per thread in build scan
#define GBLK  512      // gather blocks (bucket quads)
#define QUADCAP 4096   // cap for a bucket-quad (mean 2048, sigma ~45)
#define EPBMAX 4096    // LDS dst staging capacity (ints)

template <bool BF16>
__global__ __launch_bounds__(256) void k_build(
        const float* __restrict__ h,
        const int* __restrict__ src,
        const int* __restrict__ dst,
        unsigned int* __restrict__ pairs,      // [NPBLK * epb]
        unsigned short* __restrict__ offs,     // [NPBLK][NBUCK+1]
        uint4* __restrict__ hbf,               // bf16 table (8 f32 -> 1 uint4)
        int E, int epb, int n8) {
    int t = threadIdx.x;
    int bid = blockIdx.x;

    if (bid >= NPBLK) {
        // ---- cvt part: f32 -> packed bf16 (RNE) ----
        if (!BF16) return;
        int i = (bid - NPBLK) * 256 + t;
        if (i >= n8) return;
        const float4* h4 = (const float4*)h;
        float4 a = h4[2 * i], bq = h4[2 * i + 1];
        auto pk = [](float lo, float hi) {
            unsigned int ul = __float_as_uint(lo), uh = __float_as_uint(hi);
            unsigned int rl = (ul + 0x7FFFu + ((ul >> 16) & 1u)) >> 16;
            unsigned int rh = (uh + 0x7FFFu + ((uh >> 16) & 1u)) & 0xFFFF0000u;
            return rl | rh;
        };
        hbf[i] = make_uint4(pk(a.x, a.y), pk(a.z, a.w), pk(bq.x, bq.y), pk(bq.z, bq.w));
        return;
    }

    // ---- partition part: local counting sort of this block's edge slice ----
    __shared__ unsigned int hist[NBUCK];    // reused as absolute cursors
    __shared__ uint4 dstbuf4[EPBMAX / 4];   // staged dst values (16 KB)
    __shared__ unsigned int wpart[4];
    for (int i = t; i < NBUCK; i += 256) hist[i] = 0u;
    __syncthreads();

    int base = bid * epb;
    int cnt = E - base; if (cnt > epb) cnt = epb; if (cnt < 0) cnt = 0;
    int nv = cnt >> 2;                      // int4 groups (epb % 4 == 0)

    // Hist pass: int4 reads (4 edges/iter), stage dst in LDS.
    const int4* d4 = (const int4*)(dst + base);
    for (int i = t; i < nv; i += 256) {
        int4 d = d4[i];
        dstbuf4[i] = make_uint4((unsigned)d.x, (unsigned)d.y,
                                (unsigned)d.z, (unsigned)d.w);
        atomicAdd(&hist[((unsigned)d.x) >> 5], 1u);
        atomicAdd(&hist[((unsigned)d.y) >> 5], 1u);
        atomicAdd(&hist[((unsigned)d.z) >> 5], 1u);
        atomicAdd(&hist[((unsigned)d.w) >> 5], 1u);
    }
    for (int i = nv * 4 + t; i < cnt; i += 256)          // tail (rare)
        atomicAdd(&hist[((unsigned)dst[base + i]) >> 5], 1u);
    __syncthreads();

    // Block-exclusive scan over 2048 bins; thread t owns bins t*8..t*8+7.
    unsigned int loc[NPT], lsum = 0u;
    #pragma unroll
    for (int i = 0; i < NPT; ++i) { loc[i] = hist[t * NPT + i]; lsum += loc[i]; }
    int lane = t & 63, wid = t >> 6;
    unsigned int x = lsum;
    #pragma unroll
    for (int off = 1; off < 64; off <<= 1) {
        unsigned int y = __shfl_up(x, off);
        if (lane >= off) x += y;
    }
    if (lane == 63) wpart[wid] = x;
    __syncthreads();
    if (wid == 0) {                        // full-wave scan of 4 partials
        unsigned int w = (lane < 4) ? wpart[lane] : 0u;
        #pragma unroll
        for (int off = 1; off < 4; off <<= 1) {
            unsigned int y = __shfl_up(w, off);
            if (lane >= off) w += y;
        }
        if (lane < 4) wpart[lane] = w;
    }
    __syncthreads();
    unsigned int run = (wid ? wpart[wid - 1] : 0u) + x - lsum;

    size_t orow = (size_t)bid * (NBUCK + 1);
    #pragma unroll
    for (int i = 0; i < NPT; ++i) {
        offs[orow + t * NPT + i] = (unsigned short)run;
        hist[t * NPT + i] = (unsigned)base + run;      // absolute cursor
        run += loc[i];
    }
    if (t == 255) offs[orow + NBUCK] = (unsigned short)cnt;
    __syncthreads();

    // Scatter pass: int4 src reads, dst from LDS; payload packs d&127
    // (node within BUCKET QUAD). Writes confined to [base, base+cnt).
    const int4* s4 = (const int4*)(src + base);
    for (int i = t; i < nv; i += 256) {
        int4 s = s4[i];
        uint4 d = dstbuf4[i];
        unsigned int p0 = atomicAdd(&hist[d.x >> 5], 1u);
        pairs[p0] = (unsigned)s.x | ((d.x & 127u) << 16);
        unsigned int p1 = atomicAdd(&hist[d.y >> 5], 1u);
        pairs[p1] = (unsigned)s.y | ((d.y & 127u) << 16);
        unsigned int p2 = atomicAdd(&hist[d.z >> 5], 1u);
        pairs[p2] = (unsigned)s.z | ((d.z & 127u) << 16);
        unsigned int p3 = atomicAdd(&hist[d.w >> 5], 1u);
        pairs[p3] = (unsigned)s.w | ((d.w & 127u) << 16);
    }
    for (int i = nv * 4 + t; i < cnt; i += 256) {        // tail (rare)
        unsigned int d = (unsigned)dst[base + i];
        unsigned int s = (unsigned)src[base + i];
        unsigned int pos = atomicAdd(&hist[d >> 5], 1u);
        pairs[pos] = s | ((d & 127u) << 16);
    }
}

// One block (16 waves, 1024 thr) per bucket QUAD (128 nodes).
template <bool BF16>
__global__ __launch_bounds__(1024) void k_gather(
        const float* __restrict__ h,          // f32 original (deg==0 fallback)
        const uint2* __restrict__ hbf,        // bf16 table, 16 uint2/node
        const unsigned int* __restrict__ pairs,
        const unsigned short* __restrict__ offs,
        float* __restrict__ out, int epb) {
    __shared__ unsigned int pairbuf[QUADCAP];        // 16 KB
    __shared__ unsigned short ssrc[QUADCAP];         // 8 KB
    __shared__ unsigned int hist[128], offl[128], cur[128];
    __shared__ unsigned int wpart[16];
    int t = threadIdx.x;
    // XCD-aware swizzle over 512 bucket-quads (bijective: 512 % 8 == 0).
    int B = blockIdx.x;
    int g = (B & 7) * (GBLK / 8) + (B >> 3);
    int b4 = 4 * g;                        // first bucket of the quad
    if (t < 128) hist[t] = 0u;

    // Phase A: 4 threads per pblock; all 4 read the combined run bounds.
    int p = t >> 2, q = t & 3;             // p in 0..255
    size_t orow = (size_t)p * (NBUCK + 1);
    unsigned int s0 = offs[orow + b4];
    unsigned int s4v = offs[orow + b4 + 4];
    unsigned int runlen = s4v - s0;
    unsigned int contrib = (q == 0) ? runlen : 0u;

    // Block scan (16 waves) of contributions -> placement.
    int lane = t & 63, wid = t >> 6;
    unsigned int x = contrib;
    #pragma unroll
    for (int off = 1; off < 64; off <<= 1) {
        unsigned int y = __shfl_up(x, off);
        if (lane >= off) x += y;
    }
    if (lane == 63) wpart[wid] = x;
    __syncthreads();                       // also covers hist zero
    if (wid == 0) {                        // full-wave scan of 16 partials
        unsigned int w = (lane < 16) ? wpart[lane] : 0u;
        #pragma unroll
        for (int off = 1; off < 16; off <<= 1) {
            unsigned int y = __shfl_up(w, off);
            if (lane >= off) w += y;
        }
        if (lane < 16) wpart[lane] = w;
    }
    __syncthreads();
    unsigned int e = (wid ? wpart[wid - 1] : 0u) + x - contrib;  // excl prefix
    unsigned int mypos = e - (q ? runlen : 0u);    // pblock p's placement
    unsigned int cnt = min(wpart[15], (unsigned)QUADCAP);
    if (mypos >= cnt) runlen = 0u;
    else if (mypos + runlen > cnt) runlen = cnt - mypos;

    // Interleaved copy: thread q of the 4 handles k = q, q+4, ...
    for (unsigned int k = (unsigned)q; k < runlen; k += 4u) {
        unsigned int pr = pairs[(size_t)p * epb + s0 + k];
        pairbuf[mypos + k] = pr;
        atomicAdd(&hist[pr >> 16], 1u);
    }
    __syncthreads();

    // Exclusive scan of 128 node counts on wave 0 (2 bins per lane).
    if (t < 64) {
        unsigned int v0 = hist[2 * t], v1 = hist[2 * t + 1];
        unsigned int v = v0 + v1;
        unsigned int xx = v;
        #pragma unroll
        for (int off = 1; off < 64; off <<= 1) {
            unsigned int y = __shfl_up(xx, off);
            if (t >= off) xx += y;
        }
        unsigned int excl = xx - v;
        offl[2 * t] = excl;          cur[2 * t] = excl;
        offl[2 * t + 1] = excl + v0; cur[2 * t + 1] = excl + v0;
    }
    __syncthreads();

    // LDS scatter into per-node sorted order (u16 src payload).
    for (unsigned int i = t; i < cnt; i += 1024u) {
        unsigned int pr = pairbuf[i];
        unsigned int pos = atomicAdd(&cur[pr >> 16], 1u);
        ssrc[pos] = (unsigned short)(pr & 0xFFFFu);
    }
    __syncthreads();

    // Gather: wave w (0..15) handles nodes w*8 .. w*8+7, processed as 4 pairs.
    int w = t >> 6;
    int egrp = lane >> 4, fq = lane & 15;
    const float4* h4 = (const float4*)h;
    float4* out4 = (float4*)out;

    for (int np = 0; np < 4; ++np) {
        int na = w * 8 + np * 2;
        int nb = na + 1;
        unsigned int sa = offl[na], da = hist[na];
        unsigned int sb = offl[nb], db = hist[nb];
        float4 accA = make_float4(0.f, 0.f, 0.f, 0.f);
        float4 accB = make_float4(0.f, 0.f, 0.f, 0.f);
        unsigned int dmax = max(da, db);
        for (unsigned int base = 0; base < dmax; base += 64u) {
            int ca = (int)min(64u, (da > base) ? (da - base) : 0u);  // uniform
            int cb = (int)min(64u, (db > base) ? (db - base) : 0u);  // uniform
            int ia = (lane < ca) ? (int)ssrc[sa + base + lane] : 0;
            int ib = (lane < cb) ? (int)ssrc[sb + base + lane] : 0;
            int cm = (ca > cb) ? ca : cb;
            int nit = (cm + 3) >> 2;                     // wave-uniform
            for (int it = 0; it < nit; ++it) {
                int j = it * 4 + egrp;
                int sA = __shfl(ia, (j < ca) ? j : 0);   // all lanes active
                int sB = __shfl(ib, (j < cb) ? j : 0);
                if (BF16) {
                    uint2 mA = hbf[(size_t)sA * 16 + fq];
                    uint2 mB = hbf[(size_t)sB * 16 + fq];
                    if (j < ca) {
                        accA.x += __uint_as_float(mA.x << 16);
                        accA.y += __uint_as_float(mA.x & 0xFFFF0000u);
                        accA.z += __uint_as_float(mA.y << 16);
                        accA.w += __uint_as_float(mA.y & 0xFFFF0000u);
                    }
                    if (j < cb) {
                        accB.x += __uint_as_float(mB.x << 16);
                        accB.y += __uint_as_float(mB.x & 0xFFFF0000u);
                        accB.z += __uint_as_float(mB.y << 16);
                        accB.w += __uint_as_float(mB.y & 0xFFFF0000u);
                    }
                } else {
                    float4 mA = h4[(size_t)sA * 16 + fq];
                    float4 mB = h4[(size_t)sB * 16 + fq];
                    if (j < ca) {
                        accA.x += mA.x; accA.y += mA.y; accA.z += mA.z; accA.w += mA.w;
                    }
                    if (j < cb) {
                        accB.x += mB.x; accB.y += mB.y; accB.z += mB.z; accB.w += mB.w;
                    }
                }
            }
        }
        // Butterfly-reduce both acc chains (xor 16, 32); sum lands in ALL lanes.
        #pragma unroll
        for (int k = 16; k <= 32; k <<= 1) {
            accA.x += __shfl_xor(accA.x, k);
            accA.y += __shfl_xor(accA.y, k);
            accA.z += __shfl_xor(accA.z, k);
            accA.w += __shfl_xor(accA.w, k);
            accB.x += __shfl_xor(accB.x, k);
            accB.y += __shfl_xor(accB.y, k);
            accB.z += __shfl_xor(accB.z, k);
            accB.w += __shfl_xor(accB.w, k);
        }
        // Lanes 0-15 store node A, lanes 16-31 store node B.
        if (lane < 32) {
            int n = (lane < 16) ? na : nb;
            unsigned int dg = (lane < 16) ? da : db;
            float4 acc = (lane < 16) ? accA : accB;
            size_t oi = ((size_t)g * 128 + n) * 16 + fq;
            float4 r;
            if (dg > 0u) {
                float inv = 1.0f / (float)dg;
                r = make_float4(acc.x * inv, acc.y * inv, acc.z * inv, acc.w * inv);
            } else {
                r = h4[oi];               // exact f32 copy
            }
            out4[oi] = r;
        }
    }
}

extern "C" void kernel_launch(void* const* d_in, const int* in_sizes, int n_in,
                              void* d_out, int out_size, void* d_ws, size_t ws_size,
                              hipStream_t stream) {
    const float* h = (const float*)d_in[0];
    const int* src = (const int*)d_in[1];
    const int* dst = (const int*)d_in[2];
    float* out = (float*)d_out;
    int E = in_sizes[1];
    int nodes = out_size / 64;        // 65536

    int epb = ((E + NPBLK - 1) / NPBLK + 255) & ~255;   // 4096 for E=1M

    // ws layout: pairs 4MB | offs 1.05MB | hbf 8MB
    unsigned int* pairs  = (unsigned int*)d_ws;
    unsigned short* offs = (unsigned short*)(pairs + (size_t)NPBLK * epb);
    size_t offs_elems = (size_t)NPBLK * (NBUCK + 1);
    size_t offs_bytes = (offs_elems * 2 + 15) & ~(size_t)15;
    uint4* hbf = (uint4*)((char*)offs + offs_bytes);

    size_t need_base = (size_t)NPBLK * epb * 4 + offs_bytes;
    size_t need_bf   = need_base + (size_t)nodes * 64 * 2;
    bool use_bf = (ws_size >= need_bf);

    int n8 = nodes * 64 / 8;                      // uint4 outputs for cvt
    int cvtblocks = (n8 + 255) / 256;

    if (use_bf) {
        k_build<true><<<NPBLK + cvtblocks, 256, 0, stream>>>(
            h, src, dst, pairs, offs, hbf, E, epb, n8);
        k_gather<true><<<GBLK, 1024, 0, stream>>>(
            h, (const uint2*)hbf, pairs, offs, out, epb);
    } else {
        k_build<false><<<NPBLK, 256, 0, stream>>>(
            h, src, dst, pairs, offs, hbf, E, epb, n8);
        k_gather<false><<<GBLK, 1024, 0, stream>>>(
            h, (const uint2*)hbf, pairs, offs, out, epb);
    }
}